// Round 7
// baseline (233.329 us; speedup 1.0000x reference)
//
#include <hip/hip_runtime.h>

typedef __bf16 bf16;
typedef __bf16 bf16x8 __attribute__((ext_vector_type(8)));
typedef __bf16 bf16x4 __attribute__((ext_vector_type(4)));
typedef __bf16 bf16x2 __attribute__((ext_vector_type(2)));
typedef float f32x4 __attribute__((ext_vector_type(4)));
typedef float f32x16 __attribute__((ext_vector_type(16)));

#define MM 4096   // B*S
#define NN 1024   // E
#define KK 1024   // E

__device__ __forceinline__ void gload_lds16(const void* g, void* l) {
  __builtin_amdgcn_global_load_lds(
      (const __attribute__((address_space(1))) void*)g,
      (__attribute__((address_space(3))) void*)l, 16, 0, 0);
}

// ---------------- fused converts: activations + weights -> bf16 ----------------
__global__ __launch_bounds__(256) void cvt_all(const float* __restrict__ q,
                                               const float* __restrict__ k,
                                               const float* __restrict__ v,
                                               const float* __restrict__ Wq,
                                               const float* __restrict__ Wk,
                                               const float* __restrict__ Wv,
                                               const float* __restrict__ Wo,
                                               bf16* __restrict__ Xb,
                                               bf16* __restrict__ Wt,
                                               bf16* __restrict__ Wot)
{
  __shared__ bf16 Sl[64 * 72];
  const int bid = blockIdx.x;
  const int t = threadIdx.x;

  if (bid < 12288) {
    int p = bid >> 12, bx = bid & 4095;
    const float* src = (p == 0) ? q : (p == 1 ? k : v);
    bf16* dst = Xb + (size_t)p * (MM * (size_t)KK);
    int i = (bx * 256 + t) * 4;
    float4 val = *(const float4*)(src + i);
    bf16x4 o;
    o.x = (bf16)val.x; o.y = (bf16)val.y; o.z = (bf16)val.z; o.w = (bf16)val.w;
    *(bf16x4*)(dst + i) = o;
    return;
  }

  const int wb = bid - 12288;          // 0..1023
  const int p = wb >> 8, t8 = wb & 255;
  const int ti = t >> 4, c4 = (t & 15) * 4;

  if (p < 3) {
    const float* W = (p == 0) ? Wq : (p == 1 ? Wk : Wv);
    const int h = t8 >> 4, e0 = (t8 & 15) << 6;
#pragma unroll
    for (int r = 0; r < 4; ++r) {
      int e_l = r * 16 + ti;
      float4 val = *(const float4*)(W + (h << 16) + (e0 + e_l) * 64 + c4);
      bf16x4 o; o.x = (bf16)val.x; o.y = (bf16)val.y; o.z = (bf16)val.z; o.w = (bf16)val.w;
      *(bf16x4*)(Sl + e_l * 72 + c4) = o;
    }
    __syncthreads();
#pragma unroll
    for (int r = 0; r < 4; ++r) {
      int d_l = r * 16 + ti;
      bf16x4 o;
      o.x = Sl[(c4 + 0) * 72 + d_l];
      o.y = Sl[(c4 + 1) * 72 + d_l];
      o.z = Sl[(c4 + 2) * 72 + d_l];
      o.w = Sl[(c4 + 3) * 72 + d_l];
      *(bf16x4*)(Wt + (size_t)p * 1048576 + (size_t)((h << 6) + d_l) * 1024 + e0 + c4) = o;
    }
  } else {
    const int n0 = (t8 >> 4) << 6, k0 = (t8 & 15) << 6;
#pragma unroll
    for (int r = 0; r < 4; ++r) {
      int k_l = r * 16 + ti;
      float4 val = *(const float4*)(Wo + (size_t)(k0 + k_l) * 1024 + n0 + c4);
      bf16x4 o; o.x = (bf16)val.x; o.y = (bf16)val.y; o.z = (bf16)val.z; o.w = (bf16)val.w;
      *(bf16x4*)(Sl + k_l * 72 + c4) = o;
    }
    __syncthreads();
#pragma unroll
    for (int r = 0; r < 4; ++r) {
      int n_l = r * 16 + ti;
      bf16x4 o;
      o.x = Sl[(c4 + 0) * 72 + n_l];
      o.y = Sl[(c4 + 1) * 72 + n_l];
      o.z = Sl[(c4 + 2) * 72 + n_l];
      o.w = Sl[(c4 + 3) * 72 + n_l];
      *(bf16x4*)(Wot + (size_t)(n0 + n_l) * 1024 + k0 + c4) = o;
    }
  }
}

// ---------------- m97-style GEMM core, BK=64 (2x unrolled, half the barriers) ----
// As/Bs are 8192 elems (16 KB) each: two m97-layout 128x32 sub-buffers at +0/+4096.
__device__ __forceinline__ void gemm_body64(const bf16* __restrict__ A,
                                            const bf16* __restrict__ Bt,
                                            bf16* As, bf16* Bs,
                                            int m0, int n0, f32x4 (&acc)[4][4])
{
  const int tid = threadIdx.x;
  const int w = tid >> 6, L = tid & 63;
  const int quad = L >> 4, l16 = L & 15;
  const int wm = (w & 1) << 6, wn = (w >> 1) << 6;

  const bf16* Ag = A + (size_t)(m0 + w * 32 + (L >> 2)) * KK + (L & 3) * 8;
  const bf16* Bg = Bt + (size_t)(n0 + w * 32 + (L >> 2)) * KK + (L & 3) * 8;
  bf16* Al = As + w * 1024;
  bf16* Bl = Bs + w * 1024;

  for (int kt = 0; kt < KK / 64; ++kt) {
    __syncthreads();
    const bf16* a0 = Ag + kt * 64;
    const bf16* b0 = Bg + kt * 64;
    gload_lds16(a0, Al);
    gload_lds16(a0 + 16 * KK, Al + 512);
    gload_lds16(a0 + 32, Al + 4096);
    gload_lds16(a0 + 16 * KK + 32, Al + 4096 + 512);
    gload_lds16(b0, Bl);
    gload_lds16(b0 + 16 * KK, Bl + 512);
    gload_lds16(b0 + 32, Bl + 4096);
    gload_lds16(b0 + 16 * KK + 32, Bl + 4096 + 512);
    __syncthreads();
#pragma unroll
    for (int ks = 0; ks < 2; ++ks) {
      bf16x8 af[4], bfr[4];
#pragma unroll
      for (int mi = 0; mi < 4; ++mi)
        af[mi] = *(const bf16x8*)(As + ks * 4096 + (wm + mi * 16 + l16) * 32 + quad * 8);
#pragma unroll
      for (int ni = 0; ni < 4; ++ni)
        bfr[ni] = *(const bf16x8*)(Bs + ks * 4096 + (wn + ni * 16 + l16) * 32 + quad * 8);
#pragma unroll
      for (int mi = 0; mi < 4; ++mi)
#pragma unroll
        for (int ni = 0; ni < 4; ++ni)
          acc[mi][ni] = __builtin_amdgcn_mfma_f32_16x16x32_bf16(af[mi], bfr[ni],
                                                                acc[mi][ni], 0, 0, 0);
    }
  }
}

__global__ __launch_bounds__(256) void gemm_proj(const bf16* __restrict__ X,
                                                 const bf16* __restrict__ Wt,
                                                 const float* __restrict__ b0,
                                                 const float* __restrict__ b1,
                                                 const float* __restrict__ b2,
                                                 bf16* __restrict__ Out)
{
  __shared__ bf16 As[8192], Bs[8192];
  int p = blockIdx.y;
  const bf16* A = X + (size_t)p * 4194304;
  const bf16* Bt = Wt + (size_t)p * 1048576;
  const float* bias = (p == 0) ? b0 : (p == 1 ? b1 : b2);
  bf16* C = Out + (size_t)p * 4194304;
  int bx = blockIdx.x;
  int m0 = (bx >> 3) << 7, n0 = (bx & 7) << 7;
  f32x4 acc[4][4] = {};
  gemm_body64(A, Bt, As, Bs, m0, n0, acc);
  const int L = threadIdx.x & 63, w = threadIdx.x >> 6;
  const int quad = L >> 4, l16 = L & 15;
  const int wm = (w & 1) << 6, wn = (w >> 1) << 6;
#pragma unroll
  for (int ni = 0; ni < 4; ++ni) {
    int col = n0 + wn + ni * 16 + l16;
    float bv = bias[col];
#pragma unroll
    for (int mi = 0; mi < 4; ++mi)
#pragma unroll
      for (int r = 0; r < 4; ++r) {
        int row = m0 + wm + mi * 16 + quad * 4 + r;
        C[(size_t)row * NN + col] = (bf16)(acc[mi][ni][r] + bv);
      }
  }
}

// ---------------- 64x128-tile output projection, BK=64 ----------------
__global__ __launch_bounds__(256) void gemm_outp(const bf16* __restrict__ A,
                                                 const bf16* __restrict__ Bt,
                                                 const float* __restrict__ bias,
                                                 float* __restrict__ C)
{
  __shared__ bf16 As[4096], Bs[8192];
  const int bx = blockIdx.x;
  const int m0 = (bx >> 3) << 6, n0 = (bx & 7) << 7;
  const int tid = threadIdx.x;
  const int w = tid >> 6, L = tid & 63;
  const int quad = L >> 4, l16 = L & 15;
  const int wm = (w & 1) << 5, wn = (w >> 1) << 6;

  const bf16* Ag = A + (size_t)(m0 + w * 16 + (L >> 2)) * KK + (L & 3) * 8;
  const bf16* Bg = Bt + (size_t)(n0 + w * 32 + (L >> 2)) * KK + (L & 3) * 8;
  bf16* Al = As + w * 512;
  bf16* Bl = Bs + w * 1024;

  f32x4 acc[2][4] = {};
  for (int kt = 0; kt < KK / 64; ++kt) {
    __syncthreads();
    const bf16* a0 = Ag + kt * 64;
    const bf16* b0 = Bg + kt * 64;
    gload_lds16(a0, Al);
    gload_lds16(a0 + 32, Al + 2048);
    gload_lds16(b0, Bl);
    gload_lds16(b0 + 16 * KK, Bl + 512);
    gload_lds16(b0 + 32, Bl + 4096);
    gload_lds16(b0 + 16 * KK + 32, Bl + 4096 + 512);
    __syncthreads();
#pragma unroll
    for (int ks = 0; ks < 2; ++ks) {
      bf16x8 af[2], bfr[4];
#pragma unroll
      for (int mi = 0; mi < 2; ++mi)
        af[mi] = *(const bf16x8*)(As + ks * 2048 + (wm + mi * 16 + l16) * 32 + quad * 8);
#pragma unroll
      for (int ni = 0; ni < 4; ++ni)
        bfr[ni] = *(const bf16x8*)(Bs + ks * 4096 + (wn + ni * 16 + l16) * 32 + quad * 8);
#pragma unroll
      for (int mi = 0; mi < 2; ++mi)
#pragma unroll
        for (int ni = 0; ni < 4; ++ni)
          acc[mi][ni] = __builtin_amdgcn_mfma_f32_16x16x32_bf16(af[mi], bfr[ni],
                                                                acc[mi][ni], 0, 0, 0);
    }
  }

#pragma unroll
  for (int ni = 0; ni < 4; ++ni) {
    int col = n0 + wn + ni * 16 + l16;
    float bv = bias[col];
#pragma unroll
    for (int mi = 0; mi < 2; ++mi)
#pragma unroll
      for (int r = 0; r < 4; ++r) {
        int row = m0 + wm + mi * 16 + quad * 4 + r;
        C[(size_t)row * NN + col] = acc[mi][ni][r] + bv;
      }
  }
}

// ---------------- flash attention v7: v6 + double-buffered K/V (1 barrier/iter)
//                  + l via VALU partials (no ones-MFMA) ----------------
// Hazard proof for 1 barrier/iter: writes to buf X in iter k only race reads of
// buf X from iter k-1, and the end-of-iter-(k-1) barrier separates them.
__global__ __launch_bounds__(256) void flash_attn(const bf16* __restrict__ Qm,
                                                  const bf16* __restrict__ Km,
                                                  const bf16* __restrict__ Vm,
                                                  bf16* __restrict__ Om)
{
  __shared__ bf16 Kl[2][4096];      // 16 KB, [stored key][dh], XOR-swizzled
  __shared__ bf16 Vt[2][4096];      // 16 KB, [dh][stored key], XOR-swizzled
  __shared__ bf16 Pl[4][2048];      // 16 KB, per-wave [q][stored key], XOR-swizzled

  const int tid = threadIdx.x;
  const int w = tid >> 6, L = tid & 63;
  const int l32 = L & 31, hi = L >> 5;
  const int bh = blockIdx.x & 31;
  const int qb = blockIdx.x >> 5;
  const int b = bh >> 4, h = bh & 15;
  const int s0 = qb << 7;                       // 128 q-rows per block
  const size_t base = (size_t)b * 2097152 + h * 64;

  // Q fragments: A[m=l32][k = s*16 + hi*8 + j], scale*log2e folded in
  bf16x8 qf[4];
  const float SL = 0.03125f * 1.44269504088896f;
  {
    const bf16* qp = Qm + base + (size_t)(s0 + w * 32 + l32) * 1024 + hi * 8;
#pragma unroll
    for (int s = 0; s < 4; ++s) {
      bf16x8 tq = *(const bf16x8*)(qp + s * 16);
#pragma unroll
      for (int j = 0; j < 8; ++j) tq[j] = (bf16)((float)tq[j] * SL);
      qf[s] = tq;
    }
  }

  f32x16 oacc0 = {}, oacc1 = {};
  float lp[16];
#pragma unroll
  for (int i = 0; i < 16; ++i) lp[i] = 0.f;

  // K staging: lane L fills Kl row L <- orig key 2*l32+hi, dh chunk [w*16,+16)
  const bf16* Kg = Km + base + (size_t)(2 * l32 + hi) * 1024 + w * 16;
  // V staging: lane L loads orig keys {2*l32, 2*l32+1} at dh slice dh8
  const int dh8 = w * 16 + hi * 8;
  const bf16* Vg = Vm + base + (size_t)(2 * l32) * 1024 + dh8;
  bf16* Pw = &Pl[w][0];
  const int r7 = l32 & 7;

  // tile 0 -> regs -> buf 0
  bf16x8 k0 = *(const bf16x8*)Kg;
  bf16x8 k1 = *(const bf16x8*)(Kg + 8);
  bf16x8 va = *(const bf16x8*)Vg;
  bf16x8 vb = *(const bf16x8*)(Vg + 1024);
  {
    bf16* KlS = &Kl[0][0];
    bf16* VtS = &Vt[0][0];
    *(bf16x8*)(KlS + L * 64 + (((2 * w + 0) ^ (L & 7)) << 3)) = k0;
    *(bf16x8*)(KlS + L * 64 + (((2 * w + 1) ^ (L & 7)) << 3)) = k1;
#pragma unroll
    for (int j = 0; j < 8; ++j) {
      int row = dh8 + j;
      bf16x2 pr; pr.x = va[j]; pr.y = vb[j];
      *(bf16x2*)(VtS + row * 64 + (((l32 >> 2) ^ (row & 7)) << 3) + ((l32 & 3) << 1)) = pr;
    }
  }
  // prefetch tile 1 into regs
  k0 = *(const bf16x8*)(Kg + 65536);
  k1 = *(const bf16x8*)(Kg + 65536 + 8);
  va = *(const bf16x8*)(Vg + 65536);
  vb = *(const bf16x8*)(Vg + 65536 + 1024);
  __syncthreads();

  for (int kt = 0; kt < 32; ++kt) {
    const int cur = kt & 1, nxt = cur ^ 1;
    const bf16* Kc = &Kl[cur][0];
    const bf16* Vc = &Vt[cur][0];

    // write tile kt+1 (in regs) into buf nxt
    if (kt + 1 < 32) {
      bf16* KlS = &Kl[nxt][0];
      bf16* VtS = &Vt[nxt][0];
      *(bf16x8*)(KlS + L * 64 + (((2 * w + 0) ^ (L & 7)) << 3)) = k0;
      *(bf16x8*)(KlS + L * 64 + (((2 * w + 1) ^ (L & 7)) << 3)) = k1;
#pragma unroll
      for (int j = 0; j < 8; ++j) {
        int row = dh8 + j;
        bf16x2 pr; pr.x = va[j]; pr.y = vb[j];
        *(bf16x2*)(VtS + row * 64 + (((l32 >> 2) ^ (row & 7)) << 3) + ((l32 & 3) << 1)) = pr;
      }
    }
    // prefetch tile kt+2 into regs
    if (kt + 2 < 32) {
      k0 = *(const bf16x8*)(Kg + (size_t)(kt + 2) * 65536);
      k1 = *(const bf16x8*)(Kg + (size_t)(kt + 2) * 65536 + 8);
      va = *(const bf16x8*)(Vg + (size_t)(kt + 2) * 65536);
      vb = *(const bf16x8*)(Vg + (size_t)(kt + 2) * 65536 + 1024);
    }

    // S = Q K^T: 32 q x 64 stored keys
    f32x16 sa = {}, sb = {};
#pragma unroll
    for (int s = 0; s < 4; ++s) {
      bf16x8 kfa = *(const bf16x8*)(Kc + (l32)      * 64 + (((2 * s + hi) ^ r7) << 3));
      bf16x8 kfb = *(const bf16x8*)(Kc + (32 + l32) * 64 + (((2 * s + hi) ^ r7) << 3));
      sa = __builtin_amdgcn_mfma_f32_32x32x16_bf16(qf[s], kfa, sa, 0, 0, 0);
      sb = __builtin_amdgcn_mfma_f32_32x32x16_bf16(qf[s], kfb, sb, 0, 0, 0);
    }

    // exp2 + l partials + packed P store
#pragma unroll
    for (int reg = 0; reg < 16; ++reg) {
      int row = (reg & 3) + ((reg >> 2) << 3) + (hi << 2);
      float p0 = __builtin_amdgcn_exp2f(sa[reg]);
      float p1 = __builtin_amdgcn_exp2f(sb[reg]);
      lp[reg] += p0 + p1;
      bf16x2 pv; pv.x = (bf16)p0; pv.y = (bf16)p1;
      *(bf16x2*)(Pw + row * 64 + (((l32 >> 2) ^ (row & 7)) << 3) + ((l32 & 3) << 1)) = pv;
    }
    asm volatile("s_waitcnt lgkmcnt(0)" ::: "memory");  // Pl is wave-local

    // O += P V^T
#pragma unroll
    for (int s = 0; s < 4; ++s) {
      bf16x8 paf = *(const bf16x8*)(Pw + l32 * 64 + (((2 * s + hi) ^ r7) << 3));
      bf16x8 vf0 = *(const bf16x8*)(Vc + (l32)      * 64 + (((2 * s + hi) ^ r7) << 3));
      bf16x8 vf1 = *(const bf16x8*)(Vc + (32 + l32) * 64 + (((2 * s + hi) ^ r7) << 3));
      oacc0 = __builtin_amdgcn_mfma_f32_32x32x16_bf16(paf, vf0, oacc0, 0, 0, 0);
      oacc1 = __builtin_amdgcn_mfma_f32_32x32x16_bf16(paf, vf1, oacc1, 0, 0, 0);
    }
    __syncthreads();  // single barrier per iteration
  }

  // ---- epilogue: reduce l across the 32 lanes of this half-wave (cols), write O ----
#pragma unroll
  for (int reg = 0; reg < 16; ++reg) {
    float l = lp[reg];
    l += __shfl_xor(l, 1);
    l += __shfl_xor(l, 2);
    l += __shfl_xor(l, 4);
    l += __shfl_xor(l, 8);
    l += __shfl_xor(l, 16);
    int row = (reg & 3) + ((reg >> 2) << 3) + (hi << 2);
    float inv = 1.f / l;
    bf16* op = Om + base + (size_t)(s0 + w * 32 + row) * 1024;
    op[l32]      = (bf16)(oacc0[reg] * inv);
    op[32 + l32] = (bf16)(oacc1[reg] * inv);
  }
}

extern "C" void kernel_launch(void* const* d_in, const int* in_sizes, int n_in,
                              void* d_out, int out_size, void* d_ws, size_t ws_size,
                              hipStream_t stream)
{
  const float* q  = (const float*)d_in[0];
  const float* k  = (const float*)d_in[1];
  const float* v  = (const float*)d_in[2];
  const float* Wq = (const float*)d_in[3];
  const float* bq = (const float*)d_in[4];
  const float* Wk = (const float*)d_in[5];
  const float* bk = (const float*)d_in[6];
  const float* Wv = (const float*)d_in[7];
  const float* bv = (const float*)d_in[8];
  const float* Wo = (const float*)d_in[9];
  const float* bo = (const float*)d_in[10];

  char* ws = (char*)d_ws;
  bf16* Xb  = (bf16*)ws;                    // 3 x 4096x1024 bf16 (dead after gemm_proj)
  bf16* Wt  = (bf16*)(ws + 25165824);       // 3 x 1024x1024 bf16
  bf16* Wot = (bf16*)(ws + 31457280);       // 1024x1024 bf16
  bf16* QKV = (bf16*)(ws + 33554432);       // 3 x 4096x1024 bf16
  bf16* O   = (bf16*)ws;                    // aliases Xb

  cvt_all<<<dim3(13312), 256, 0, stream>>>(q, k, v, Wq, Wk, Wv, Wo, Xb, Wt, Wot);
  gemm_proj<<<dim3(256, 3), 256, 0, stream>>>(Xb, Wt, bq, bk, bv, QKV);
  flash_attn<<<dim3(512), 256, 0, stream>>>(QKV, QKV + 4194304, QKV + 8388608, O);
  gemm_outp<<<dim3(512), 256, 0, stream>>>(O, Wot, bo, (float*)d_out);
}